// Round 13
// baseline (32.574 us; speedup 1.0000x reference)
//
#include <hip/hip_runtime.h>
#include <math.h>

#define BSZ 512
#define DSZ 512
#define MARGIN 0.4f
#define ALPHA 1.0f

typedef unsigned int u32;
typedef __attribute__((ext_vector_type(8))) short bf16x8;
typedef __attribute__((ext_vector_type(4))) float f32x4;

static __device__ __forceinline__ u32 pack_bf16x2(float a, float b) {
    u32 ua = __float_as_uint(a);
    ua = (ua + 0x7fffu + ((ua >> 16) & 1u)) >> 16;
    u32 ub = __float_as_uint(b);
    ub = (ub + 0x7fffu + ((ub >> 16) & 1u)) & 0xffff0000u;
    return ua | ub;
}

static __device__ __forceinline__ bf16x8 pack8(const float4 a, const float4 b) {
    union { u32 u[4]; bf16x8 v; } r;
    r.u[0] = pack_bf16x2(a.x, a.y);
    r.u[1] = pack_bf16x2(a.z, a.w);
    r.u[2] = pack_bf16x2(b.x, b.y);
    r.u[3] = pack_bf16x2(b.z, b.w);
    return r.v;
}

// ---- K1: fused norms + on-the-fly bf16 MFMA dist (LDS-free frags) ----
// 256 blocks (16x16 of 32x32 tiles) x 256 threads (4 waves = 2x2 16x16
// quadrants). Fragments converted from f32 emb in registers; row sumsq
// accumulated during load (exact f32), reduced over the 4 lanes sharing
// a row; dist = sqrt(max(2 - 2*dot*inv_i*inv_j, 0)).
__global__ __launch_bounds__(256) void rll_dist(const float* __restrict__ emb,
                                                float* __restrict__ dist,
                                                int* __restrict__ counter) {
    __shared__ float invA[2][16];
    __shared__ float invB[2][16];
    const int tid = threadIdx.x;
    const int w = tid >> 6, l = tid & 63;
    const int wr = w >> 1, wc = w & 1;
    const int brow = blockIdx.y * 32, bcol = blockIdx.x * 32;
    const int fr = l & 15;
    const int fkq = l >> 4;                  // k-quarter within 32-chunk
    if (blockIdx.x == 0 && blockIdx.y == 0 && tid == 0) counter[0] = 0;

    const float* arow = emb + (size_t)(brow + wr * 16 + fr) * DSZ + fkq * 8;
    const float* brw  = emb + (size_t)(bcol + wc * 16 + fr) * DSZ + fkq * 8;

    float ssa = 0.f, ssb = 0.f;
    bf16x8 afrag[16];
    #pragma unroll
    for (int kc = 0; kc < 16; ++kc) {
        const float4 a0 = *(const float4*)(arow + kc * 32);
        const float4 a1 = *(const float4*)(arow + kc * 32 + 4);
        ssa += a0.x * a0.x + a0.y * a0.y + a0.z * a0.z + a0.w * a0.w
             + a1.x * a1.x + a1.y * a1.y + a1.z * a1.z + a1.w * a1.w;
        afrag[kc] = pack8(a0, a1);
    }
    f32x4 acc = {0.f, 0.f, 0.f, 0.f};
    #pragma unroll
    for (int kc = 0; kc < 16; ++kc) {
        const float4 b0 = *(const float4*)(brw + kc * 32);
        const float4 b1 = *(const float4*)(brw + kc * 32 + 4);
        ssb += b0.x * b0.x + b0.y * b0.y + b0.z * b0.z + b0.w * b0.w
             + b1.x * b1.x + b1.y * b1.y + b1.z * b1.z + b1.w * b1.w;
        acc = __builtin_amdgcn_mfma_f32_16x16x32_bf16(afrag[kc], pack8(b0, b1),
                                                      acc, 0, 0, 0);
    }

    // row sumsq: row fr is covered by lanes {fr, fr+16, fr+32, fr+48}
    ssa += __shfl_xor(ssa, 16); ssa += __shfl_xor(ssa, 32);
    ssb += __shfl_xor(ssb, 16); ssb += __shfl_xor(ssb, 32);
    if (l < 16) {
        invA[wr][l] = 1.0f / fmaxf(sqrtf(ssa), 1e-12f);  // benign dup across wc
        invB[wc][l] = 1.0f / fmaxf(sqrtf(ssb), 1e-12f);  // benign dup across wr
    }
    __syncthreads();

    // D: col = l&15, row = (l>>4)*4 + r  (R7/R12-verified)
    const int col = bcol + wc * 16 + fr;
    const int rloc = (l >> 4) << 2;
    const int rowbase = brow + wr * 16 + rloc;
    const float ib = invB[wc][fr];
    #pragma unroll
    for (int r = 0; r < 4; ++r) {
        const float d = sqrtf(fmaxf(2.0f - 2.0f * acc[r] * invA[wr][rloc + r] * ib, 0.0f));
        dist[(size_t)(rowbase + r) * BSZ + col] = d;
    }
}

// ---- K2: counting + last-block final reduce --------------------------
// 512 blocks x 256 threads (4 waves).
__global__ __launch_bounds__(256) void rll_count(const float* __restrict__ dist,
                                                 const int* __restrict__ labels,
                                                 float* __restrict__ partial,
                                                 int* __restrict__ counter,
                                                 float* __restrict__ out) {
    __shared__ float dsh[BSZ];
    __shared__ int   lsh[BSZ];
    __shared__ int   pos[128];
    __shared__ int   npos;
    __shared__ float wsum[4];
    __shared__ bool  last;
    const int i = blockIdx.x;
    const int tid = threadIdx.x;
    if (tid == 0) npos = 0;
    if (tid < 128) {
        *(float4*)&dsh[tid * 4] = ((const float4*)(dist + (size_t)i * BSZ))[tid];
        *(int4*)&lsh[tid * 4]   = ((const int4*)labels)[tid];
    }
    __syncthreads();
    const int li = lsh[i];
    for (int j = tid; j < BSZ; j += 256) {
        if (j != i && lsh[j] == li) {
            const int idx = atomicAdd(&npos, 1);
            if (idx < 128) pos[idx] = j;
        }
    }
    if (tid < 4) wsum[tid] = 0.f;
    __syncthreads();
    const int wave = tid >> 6, lane = tid & 63;
    const int np = min(npos, 128);
    float acc = 0.f;
    for (int p = wave; p < np; p += 4) {
        const int j = pos[p];
        const float thr = dsh[j] + MARGIN;
        int cnt = 0;
        #pragma unroll
        for (int q = 0; q < 8; ++q) {
            const int k = lane + q * 64;
            cnt += (lsh[k] != li && dsh[k] < thr) ? 1 : 0;
        }
        #pragma unroll
        for (int off = 32; off > 0; off >>= 1) cnt += __shfl_down(cnt, off);
        if (lane == 0 && cnt > 0) acc += log1pf((float)cnt);
    }
    if (lane == 0) wsum[wave] = acc;
    __syncthreads();
    if (tid == 0) {
        partial[i] = wsum[0] + wsum[1] + wsum[2] + wsum[3];
        __threadfence();
        const int old = atomicAdd(counter, 1);
        last = (old == BSZ - 1);
    }
    __syncthreads();
    if (last) {
        __threadfence();
        if (tid < 64) {
            volatile const float* vp = (volatile const float*)partial;
            float s = 0.f;
            #pragma unroll
            for (int q = 0; q < BSZ / 64; ++q) s += vp[tid + q * 64];
            #pragma unroll
            for (int off = 32; off > 0; off >>= 1) s += __shfl_down(s, off);
            if (tid == 0) out[0] = s * (ALPHA / (512.0f + 1e-8f));
        }
    }
}

extern "C" void kernel_launch(void* const* d_in, const int* in_sizes, int n_in,
                              void* d_out, int out_size, void* d_ws, size_t ws_size,
                              hipStream_t stream) {
    const float* emb    = (const float*)d_in[0];
    const int*   labels = (const int*)d_in[1];
    float* out = (float*)d_out;

    // ws: dist (512*512 f32) | partial (512 f32) | counter (int)
    float* dist    = (float*)d_ws;
    float* partial = dist + (size_t)BSZ * BSZ;
    int*   counter = (int*)(partial + BSZ);

    rll_dist<<<dim3(16, 16), 256, 0, stream>>>(emb, dist, counter);
    rll_count<<<BSZ, 256, 0, stream>>>(dist, labels, partial, counter, out);
}

// Round 14
// 30.119 us; speedup vs baseline: 1.0815x; 1.0815x over previous
//
#include <hip/hip_runtime.h>
#include <math.h>

#define BSZ 512
#define DSZ 512
#define MARGIN 0.4f
#define ALPHA 1.0f

typedef unsigned int u32;
typedef __attribute__((ext_vector_type(8))) short bf16x8;
typedef __attribute__((ext_vector_type(4))) float f32x4;

static __device__ __forceinline__ u32 pack_bf16x2(float a, float b) {
    u32 ua = __float_as_uint(a);
    ua = (ua + 0x7fffu + ((ua >> 16) & 1u)) >> 16;
    u32 ub = __float_as_uint(b);
    ub = (ub + 0x7fffu + ((ub >> 16) & 1u)) & 0xffff0000u;
    return ua | ub;
}

// ---- K0: exact f32 norms + normalize + bf16 row-major (coalesced) ----
// 64 blocks x 512 threads; wave w owns row r = 8*bid + w.  (R12-proven)
__global__ __launch_bounds__(512) void rll_prep(const float* __restrict__ emb,
                                                u32* __restrict__ enr) {
    const int w = threadIdx.x >> 6, l = threadIdx.x & 63;
    const int r = blockIdx.x * 8 + w;
    const float4* src = (const float4*)(emb + (size_t)r * DSZ);
    float4 v0 = src[l * 2];
    float4 v1 = src[l * 2 + 1];
    float ss = v0.x * v0.x + v0.y * v0.y + v0.z * v0.z + v0.w * v0.w
             + v1.x * v1.x + v1.y * v1.y + v1.z * v1.z + v1.w * v1.w;
    #pragma unroll
    for (int off = 32; off > 0; off >>= 1) ss += __shfl_xor(ss, off);
    const float inv = 1.0f / fmaxf(sqrtf(ss), 1e-12f);
    v0.x *= inv; v0.y *= inv; v0.z *= inv; v0.w *= inv;
    v1.x *= inv; v1.y *= inv; v1.z *= inv; v1.w *= inv;
    *(uint4*)&enr[(size_t)r * 256 + l * 4] =
        make_uint4(pack_bf16x2(v0.x, v0.y), pack_bf16x2(v0.z, v0.w),
                   pack_bf16x2(v1.x, v1.y), pack_bf16x2(v1.z, v1.w));
}

// ---- K1: LDS-free MFMA dist tile (R12-proven) ------------------------
// 256 blocks (16x16 of 32x32 tiles) x 256 threads (4 waves = 2x2 16x16
// quadrants). Fragments straight from L2-resident ENR.
__global__ __launch_bounds__(256) void rll_dist(const u32* __restrict__ enr,
                                                float* __restrict__ dist) {
    const int tid = threadIdx.x;
    const int w = tid >> 6, l = tid & 63;
    const int wr = w >> 1, wc = w & 1;
    const int brow = blockIdx.y * 32, bcol = blockIdx.x * 32;
    const int fr = l & 15;
    const int fk = (l >> 4) * 4;            // u32 offset within 32-elem chunk

    const u32* arow  = enr + (size_t)(brow + wr * 16 + fr) * 256 + fk;
    const u32* brow_ = enr + (size_t)(bcol + wc * 16 + fr) * 256 + fk;

    bf16x8 afrag[16];
    #pragma unroll
    for (int kc = 0; kc < 16; ++kc)
        afrag[kc] = *(const bf16x8*)(arow + kc * 16);

    f32x4 acc = {0.f, 0.f, 0.f, 0.f};
    #pragma unroll
    for (int kc = 0; kc < 16; ++kc) {
        const bf16x8 b = *(const bf16x8*)(brow_ + kc * 16);
        acc = __builtin_amdgcn_mfma_f32_16x16x32_bf16(afrag[kc], b, acc, 0, 0, 0);
    }

    // D: col = l&15, row = (l>>4)*4 + r  (verified)
    const int col = bcol + wc * 16 + fr;
    const int rowbase = brow + wr * 16 + ((l >> 4) << 2);
    #pragma unroll
    for (int r = 0; r < 4; ++r)
        dist[(size_t)(rowbase + r) * BSZ + col] =
            sqrtf(fmaxf(2.0f - 2.0f * acc[r], 0.0f));
}

// ---- K2: counting, 2 anchors/block, no global atomics ----------------
// 256 blocks x 256 threads (4 waves; waves {0,2}->anchor 2b, {1,3}->2b+1).
__global__ __launch_bounds__(256) void rll_count(const float* __restrict__ dist,
                                                 const int* __restrict__ labels,
                                                 float* __restrict__ partial) {
    __shared__ float dsh[2][BSZ];
    __shared__ int   lsh[BSZ];
    __shared__ int   pos[2][128];
    __shared__ int   npos[2];
    __shared__ float wsum[4];
    const int tid = threadIdx.x;
    const int i0 = blockIdx.x * 2, i1 = i0 + 1;
    if (tid < 2) npos[tid] = 0;
    {
        const int s = tid >> 7;       // which anchor's dist row
        const int t = tid & 127;
        *(float4*)&dsh[s][t * 4] = ((const float4*)(dist + (size_t)(i0 + s) * BSZ))[t];
        if (s == 0) *(int4*)&lsh[t * 4] = ((const int4*)labels)[t];
    }
    __syncthreads();
    const int l0 = lsh[i0], l1 = lsh[i1];
    for (int j = tid; j < BSZ; j += 256) {
        const int lj = lsh[j];
        if (lj == l0 && j != i0) {
            const int idx = atomicAdd(&npos[0], 1);
            if (idx < 128) pos[0][idx] = j;
        }
        if (lj == l1 && j != i1) {
            const int idx = atomicAdd(&npos[1], 1);
            if (idx < 128) pos[1][idx] = j;
        }
    }
    if (tid < 4) wsum[tid] = 0.f;
    __syncthreads();
    const int w = tid >> 6, lane = tid & 63;
    const int s = w & 1;
    const int li = s ? l1 : l0;
    const int n = min(npos[s], 128);
    float acc = 0.f;
    for (int p = (w >> 1); p < n; p += 2) {
        const int j = pos[s][p];
        const float thr = dsh[s][j] + MARGIN;
        int cnt = 0;
        #pragma unroll
        for (int q = 0; q < 8; ++q) {
            const int k = lane + q * 64;
            cnt += (lsh[k] != li && dsh[s][k] < thr) ? 1 : 0;
        }
        #pragma unroll
        for (int off = 32; off > 0; off >>= 1) cnt += __shfl_down(cnt, off);
        if (lane == 0 && cnt > 0) acc += log1pf((float)cnt);
    }
    if (lane == 0) wsum[w] = acc;
    __syncthreads();
    if (tid == 0)
        partial[blockIdx.x] = wsum[0] + wsum[1] + wsum[2] + wsum[3];  // unconditional
}

// ---- K3: 256-partial reduce -> out[0] --------------------------------
__global__ __launch_bounds__(64) void rll_reduce(const float* __restrict__ partial,
                                                 float* __restrict__ out) {
    const int lane = threadIdx.x;
    float s = 0.f;
    #pragma unroll
    for (int q = 0; q < 4; ++q) s += partial[lane + q * 64];
    #pragma unroll
    for (int off = 32; off > 0; off >>= 1) s += __shfl_down(s, off);
    if (lane == 0) out[0] = s * (ALPHA / (512.0f + 1e-8f));
}

extern "C" void kernel_launch(void* const* d_in, const int* in_sizes, int n_in,
                              void* d_out, int out_size, void* d_ws, size_t ws_size,
                              hipStream_t stream) {
    const float* emb    = (const float*)d_in[0];
    const int*   labels = (const int*)d_in[1];
    float* out = (float*)d_out;

    // ws: ENR (512*256 u32) | dist (512*512 f32) | partial (256 f32)
    u32*   enr     = (u32*)d_ws;
    float* dist    = (float*)(enr + (size_t)BSZ * 256);
    float* partial = dist + (size_t)BSZ * BSZ;

    rll_prep<<<64, 512, 0, stream>>>(emb, enr);
    rll_dist<<<dim3(16, 16), 256, 0, stream>>>(enr, dist);
    rll_count<<<256, 256, 0, stream>>>(dist, labels, partial);
    rll_reduce<<<1, 64, 0, stream>>>(partial, out);
}

// Round 15
// 25.744 us; speedup vs baseline: 1.2653x; 1.1699x over previous
//
#include <hip/hip_runtime.h>
#include <math.h>

#define BSZ 512
#define DSZ 512
#define MARGIN 0.4f
#define ALPHA 1.0f

typedef unsigned int u32;
typedef __attribute__((ext_vector_type(8))) short bf16x8;
typedef __attribute__((ext_vector_type(4))) float f32x4;

static __device__ __forceinline__ u32 pack_bf16x2(float a, float b) {
    u32 ua = __float_as_uint(a);
    ua = (ua + 0x7fffu + ((ua >> 16) & 1u)) >> 16;
    u32 ub = __float_as_uint(b);
    ub = (ub + 0x7fffu + ((ub >> 16) & 1u)) & 0xffff0000u;
    return ua | ub;
}

// ---- K0: exact f32 norms + normalize + bf16 row-major (coalesced) ----
// 64 blocks x 512 threads; wave w owns row r = 8*bid + w.
__global__ __launch_bounds__(512) void rll_prep(const float* __restrict__ emb,
                                                u32* __restrict__ enr) {
    const int w = threadIdx.x >> 6, l = threadIdx.x & 63;
    const int r = blockIdx.x * 8 + w;
    const float4* src = (const float4*)(emb + (size_t)r * DSZ);
    float4 v0 = src[l * 2];
    float4 v1 = src[l * 2 + 1];
    float ss = v0.x * v0.x + v0.y * v0.y + v0.z * v0.z + v0.w * v0.w
             + v1.x * v1.x + v1.y * v1.y + v1.z * v1.z + v1.w * v1.w;
    #pragma unroll
    for (int off = 32; off > 0; off >>= 1) ss += __shfl_xor(ss, off);
    const float inv = 1.0f / fmaxf(sqrtf(ss), 1e-12f);
    v0.x *= inv; v0.y *= inv; v0.z *= inv; v0.w *= inv;
    v1.x *= inv; v1.y *= inv; v1.z *= inv; v1.w *= inv;
    *(uint4*)&enr[(size_t)r * 256 + l * 4] =
        make_uint4(pack_bf16x2(v0.x, v0.y), pack_bf16x2(v0.z, v0.w),
                   pack_bf16x2(v1.x, v1.y), pack_bf16x2(v1.z, v1.w));
}

// ---- K1: LDS-free MFMA dist tile ------------------------------------
// 256 blocks (16x16 of 32x32 tiles) x 256 threads (4 waves, 2x2 quadrants
// of 16x16 frags). Fragments straight from L2-resident ENR; per wave:
// 16 A-loads + 16 B-loads + 16 MFMA. dist = sqrt(max(2-2*dot,0)).
__global__ __launch_bounds__(256) void rll_dist(const u32* __restrict__ enr,
                                                float* __restrict__ dist) {
    const int tid = threadIdx.x;
    const int w = tid >> 6, l = tid & 63;
    const int wr = w >> 1, wc = w & 1;
    const int brow = blockIdx.y * 32, bcol = blockIdx.x * 32;
    const int fr = l & 15;
    const int fk = (l >> 4) * 4;            // u32 offset within 32-elem chunk

    const u32* arow = enr + (size_t)(brow + wr * 16 + fr) * 256 + fk;
    const u32* brow_ = enr + (size_t)(bcol + wc * 16 + fr) * 256 + fk;

    bf16x8 afrag[16];
    #pragma unroll
    for (int kc = 0; kc < 16; ++kc)
        afrag[kc] = *(const bf16x8*)(arow + kc * 16);

    f32x4 acc = {0.f, 0.f, 0.f, 0.f};
    #pragma unroll
    for (int kc = 0; kc < 16; ++kc) {
        const bf16x8 b = *(const bf16x8*)(brow_ + kc * 16);
        acc = __builtin_amdgcn_mfma_f32_16x16x32_bf16(afrag[kc], b, acc, 0, 0, 0);
    }

    // D: col = l&15, row = (l>>4)*4 + r  (R7-verified)
    const int col = bcol + wc * 16 + fr;
    const int rowbase = brow + wr * 16 + ((l >> 4) << 2);
    #pragma unroll
    for (int r = 0; r < 4; ++r)
        dist[(size_t)(rowbase + r) * BSZ + col] =
            sqrtf(fmaxf(2.0f - 2.0f * acc[r], 0.0f));
}

// ---- K2: ranked-list counting, per-anchor partial (no atomics) -------
// 512 blocks x 256 threads (4 waves).
__global__ __launch_bounds__(256) void rll_count(const float* __restrict__ dist,
                                                 const int* __restrict__ labels,
                                                 float* __restrict__ partial) {
    __shared__ float dsh[BSZ];
    __shared__ int   lsh[BSZ];
    __shared__ int   pos[128];
    __shared__ int   npos;
    __shared__ float wsum[4];
    const int i = blockIdx.x;
    const int tid = threadIdx.x;
    if (tid == 0) npos = 0;
    if (tid < 128) {
        *(float4*)&dsh[tid * 4] = ((const float4*)(dist + (size_t)i * BSZ))[tid];
        *(int4*)&lsh[tid * 4]   = ((const int4*)labels)[tid];
    }
    __syncthreads();
    const int li = lsh[i];
    for (int j = tid; j < BSZ; j += 256) {
        if (j != i && lsh[j] == li) {
            const int idx = atomicAdd(&npos, 1);
            if (idx < 128) pos[idx] = j;
        }
    }
    if (tid < 4) wsum[tid] = 0.f;
    __syncthreads();
    const int wave = tid >> 6, lane = tid & 63;
    const int np = min(npos, 128);
    float acc = 0.f;
    for (int p = wave; p < np; p += 4) {
        const int j = pos[p];
        const float thr = dsh[j] + MARGIN;
        int cnt = 0;
        #pragma unroll
        for (int q = 0; q < 8; ++q) {
            const int k = lane + q * 64;
            cnt += (lsh[k] != li && dsh[k] < thr) ? 1 : 0;
        }
        #pragma unroll
        for (int off = 32; off > 0; off >>= 1) cnt += __shfl_down(cnt, off);
        if (lane == 0 && cnt > 0) acc += log1pf((float)cnt);
    }
    if (lane == 0) wsum[wave] = acc;
    __syncthreads();
    if (tid == 0)
        partial[i] = wsum[0] + wsum[1] + wsum[2] + wsum[3];  // unconditional
}

// ---- K3: 512-partial reduce -> out[0] --------------------------------
__global__ __launch_bounds__(64) void rll_reduce(const float* __restrict__ partial,
                                                 float* __restrict__ out) {
    const int lane = threadIdx.x;
    float s = 0.f;
    #pragma unroll
    for (int q = 0; q < BSZ / 64; ++q) s += partial[lane + q * 64];
    #pragma unroll
    for (int off = 32; off > 0; off >>= 1) s += __shfl_down(s, off);
    if (lane == 0) out[0] = s * (ALPHA / (512.0f + 1e-8f));
}

extern "C" void kernel_launch(void* const* d_in, const int* in_sizes, int n_in,
                              void* d_out, int out_size, void* d_ws, size_t ws_size,
                              hipStream_t stream) {
    const float* emb    = (const float*)d_in[0];
    const int*   labels = (const int*)d_in[1];
    float* out = (float*)d_out;

    // ws: ENR (512*256 u32) | dist (512*512 f32) | partial (512 f32)
    u32*   enr     = (u32*)d_ws;
    float* dist    = (float*)(enr + (size_t)BSZ * 256);
    float* partial = dist + (size_t)BSZ * BSZ;

    rll_prep<<<64, 512, 0, stream>>>(emb, enr);
    rll_dist<<<dim3(16, 16), 256, 0, stream>>>(enr, dist);
    rll_count<<<BSZ, 256, 0, stream>>>(dist, labels, partial);
    rll_reduce<<<1, 64, 0, stream>>>(partial, out);
}

// Round 16
// 25.193 us; speedup vs baseline: 1.2929x; 1.0219x over previous
//
#include <hip/hip_runtime.h>
#include <math.h>

#define BSZ 512
#define DSZ 512
#define MARGIN 0.4f
#define ALPHA 1.0f

typedef unsigned int u32;
typedef unsigned short u16;
typedef __attribute__((ext_vector_type(8))) short bf16x8;
typedef __attribute__((ext_vector_type(4))) float f32x4;

static __device__ __forceinline__ u32 pack_bf16x2(float a, float b) {
    u32 ua = __float_as_uint(a);
    ua = (ua + 0x7fffu + ((ua >> 16) & 1u)) >> 16;
    u32 ub = __float_as_uint(b);
    ub = (ub + 0x7fffu + ((ub >> 16) & 1u)) & 0xffff0000u;
    return ua | ub;
}

static __device__ __forceinline__ u16 pack_bf16(float a) {
    u32 ua = __float_as_uint(a);
    return (u16)((ua + 0x7fffu + ((ua >> 16) & 1u)) >> 16);
}

// ---- K0: exact f32 norms + normalize + bf16 row-major (coalesced) ----
// 64 blocks x 512 threads; wave w owns row r = 8*bid + w.  (R12-proven)
__global__ __launch_bounds__(512) void rll_prep(const float* __restrict__ emb,
                                                u32* __restrict__ enr) {
    const int w = threadIdx.x >> 6, l = threadIdx.x & 63;
    const int r = blockIdx.x * 8 + w;
    const float4* src = (const float4*)(emb + (size_t)r * DSZ);
    float4 v0 = src[l * 2];
    float4 v1 = src[l * 2 + 1];
    float ss = v0.x * v0.x + v0.y * v0.y + v0.z * v0.z + v0.w * v0.w
             + v1.x * v1.x + v1.y * v1.y + v1.z * v1.z + v1.w * v1.w;
    #pragma unroll
    for (int off = 32; off > 0; off >>= 1) ss += __shfl_xor(ss, off);
    const float inv = 1.0f / fmaxf(sqrtf(ss), 1e-12f);
    v0.x *= inv; v0.y *= inv; v0.z *= inv; v0.w *= inv;
    v1.x *= inv; v1.y *= inv; v1.z *= inv; v1.w *= inv;
    *(uint4*)&enr[(size_t)r * 256 + l * 4] =
        make_uint4(pack_bf16x2(v0.x, v0.y), pack_bf16x2(v0.z, v0.w),
                   pack_bf16x2(v1.x, v1.y), pack_bf16x2(v1.z, v1.w));
}

// ---- K1: LDS-free MFMA dist tile, bf16 dist output -------------------
// 256 blocks (16x16 of 32x32 tiles) x 256 threads (4 waves, 2x2 quadrants
// of 16x16 frags). Fragments straight from L2-resident ENR.
__global__ __launch_bounds__(256) void rll_dist(const u32* __restrict__ enr,
                                                u16* __restrict__ distb) {
    const int tid = threadIdx.x;
    const int w = tid >> 6, l = tid & 63;
    const int wr = w >> 1, wc = w & 1;
    const int brow = blockIdx.y * 32, bcol = blockIdx.x * 32;
    const int fr = l & 15;
    const int fk = (l >> 4) * 4;            // u32 offset within 32-elem chunk

    const u32* arow  = enr + (size_t)(brow + wr * 16 + fr) * 256 + fk;
    const u32* brow_ = enr + (size_t)(bcol + wc * 16 + fr) * 256 + fk;

    bf16x8 afrag[16];
    #pragma unroll
    for (int kc = 0; kc < 16; ++kc)
        afrag[kc] = *(const bf16x8*)(arow + kc * 16);

    f32x4 acc = {0.f, 0.f, 0.f, 0.f};
    #pragma unroll
    for (int kc = 0; kc < 16; ++kc) {
        const bf16x8 b = *(const bf16x8*)(brow_ + kc * 16);
        acc = __builtin_amdgcn_mfma_f32_16x16x32_bf16(afrag[kc], b, acc, 0, 0, 0);
    }

    // D: col = l&15, row = (l>>4)*4 + r  (verified)
    const int col = bcol + wc * 16 + fr;
    const int rowbase = brow + wr * 16 + ((l >> 4) << 2);
    #pragma unroll
    for (int r = 0; r < 4; ++r) {
        const float d = sqrtf(fmaxf(2.0f - 2.0f * acc[r], 0.0f));
        distb[(size_t)(rowbase + r) * BSZ + col] = pack_bf16(d);
    }
}

// ---- K2: ranked-list counting, per-anchor partial (no atomics) -------
// 512 blocks x 256 threads (4 waves). Row unpacked bf16->f32 once at load.
__global__ __launch_bounds__(256) void rll_count(const u16* __restrict__ distb,
                                                 const int* __restrict__ labels,
                                                 float* __restrict__ partial) {
    __shared__ float dsh[BSZ];
    __shared__ int   lsh[BSZ];
    __shared__ int   pos[128];
    __shared__ int   npos;
    __shared__ float wsum[4];
    const int i = blockIdx.x;
    const int tid = threadIdx.x;
    if (tid == 0) npos = 0;
    if (tid < 128) {
        const uint2 dv = ((const uint2*)(distb + (size_t)i * BSZ))[tid];  // 4 bf16
        dsh[tid * 4 + 0] = __uint_as_float(dv.x << 16);
        dsh[tid * 4 + 1] = __uint_as_float(dv.x & 0xffff0000u);
        dsh[tid * 4 + 2] = __uint_as_float(dv.y << 16);
        dsh[tid * 4 + 3] = __uint_as_float(dv.y & 0xffff0000u);
        *(int4*)&lsh[tid * 4] = ((const int4*)labels)[tid];
    }
    __syncthreads();
    const int li = lsh[i];
    for (int j = tid; j < BSZ; j += 256) {
        if (j != i && lsh[j] == li) {
            const int idx = atomicAdd(&npos, 1);
            if (idx < 128) pos[idx] = j;
        }
    }
    if (tid < 4) wsum[tid] = 0.f;
    __syncthreads();
    const int wave = tid >> 6, lane = tid & 63;
    const int np = min(npos, 128);
    float acc = 0.f;
    for (int p = wave; p < np; p += 4) {
        const int j = pos[p];
        const float thr = dsh[j] + MARGIN;
        int cnt = 0;
        #pragma unroll
        for (int q = 0; q < 8; ++q) {
            const int k = lane + q * 64;
            cnt += (lsh[k] != li && dsh[k] < thr) ? 1 : 0;
        }
        #pragma unroll
        for (int off = 32; off > 0; off >>= 1) cnt += __shfl_down(cnt, off);
        if (lane == 0 && cnt > 0) acc += log1pf((float)cnt);
    }
    if (lane == 0) wsum[wave] = acc;
    __syncthreads();
    if (tid == 0)
        partial[i] = wsum[0] + wsum[1] + wsum[2] + wsum[3];  // unconditional
}

// ---- K3: 512-partial reduce -> out[0] --------------------------------
__global__ __launch_bounds__(64) void rll_reduce(const float* __restrict__ partial,
                                                 float* __restrict__ out) {
    const int lane = threadIdx.x;
    float s = 0.f;
    #pragma unroll
    for (int q = 0; q < BSZ / 64; ++q) s += partial[lane + q * 64];
    #pragma unroll
    for (int off = 32; off > 0; off >>= 1) s += __shfl_down(s, off);
    if (lane == 0) out[0] = s * (ALPHA / (512.0f + 1e-8f));
}

extern "C" void kernel_launch(void* const* d_in, const int* in_sizes, int n_in,
                              void* d_out, int out_size, void* d_ws, size_t ws_size,
                              hipStream_t stream) {
    const float* emb    = (const float*)d_in[0];
    const int*   labels = (const int*)d_in[1];
    float* out = (float*)d_out;

    // ws: ENR (512*256 u32) | distb (512*512 u16) | partial (512 f32)
    u32*   enr     = (u32*)d_ws;
    u16*   distb   = (u16*)(enr + (size_t)BSZ * 256);
    float* partial = (float*)(distb + (size_t)BSZ * BSZ);

    rll_prep<<<64, 512, 0, stream>>>(emb, enr);
    rll_dist<<<dim3(16, 16), 256, 0, stream>>>(enr, distb);
    rll_count<<<BSZ, 256, 0, stream>>>(distb, labels, partial);
    rll_reduce<<<1, 64, 0, stream>>>(partial, out);
}